// Round 8
// baseline (382.070 us; speedup 1.0000x reference)
//
#include <hip/hip_runtime.h>
#include <math.h>

// Problem constants (from reference): x[B][L][D] fp32
#define B 8
#define L 4096
#define D 512
#define LC 64               // chunk length
#define CK (L / LC)         // 64 chunks
#define BLD ((size_t)B * L * D)

#define NTHREADS (B * CK * D)        // 262144
#define NBLOCKS (NTHREADS / 256)     // 1024 = exactly 4 blocks/CU on 256 CUs

// ws layout: le [B][CK][D][2] floats (2 MiB), then a 64B-aligned counter.
#define LE_FLOATS (2 * B * CK * D)
#define CNT_BYTE_OFF ((size_t)LE_FLOATS * sizeof(float))
#define WS_NEED (CNT_BYTE_OFF + 64)

typedef float v2f __attribute__((ext_vector_type(2)));

// phazor = exp(-|z|^2) * z/|z|   (no trig needed)
__device__ __forceinline__ v2f phazor_of(const float* __restrict__ pparam, int d) {
    float a = pparam[d * 2 + 0];
    float bb = pparam[d * 2 + 1];
    float r2 = fmaf(a, a, bb * bb);
    float inv = rsqrtf(r2);
    inv = inv * fmaf(-0.5f * r2 * inv, inv, 1.5f);   // Newton refinement
    float mag = __expf(-r2);
    v2f p; p.x = mag * a * inv; p.y = mag * bb * inv;
    return p;
}

// Fused: phase 1 local scan (x kept in VGPRs) -> grid barrier -> phase 2
// Horner carry + output. Requires all NBLOCKS co-resident (4 blocks/CU,
// enforced by __launch_bounds__(256,4), LDS=0).
// MODE 0: out = [real plane][real plane];  MODE 1: [real][interleaved re,im]
template <int MODE>
__global__ __launch_bounds__(256, 4) void fused_k(const float* __restrict__ x,
                                                  const float* __restrict__ hr,
                                                  const float* __restrict__ hi,
                                                  const float* __restrict__ pinit,
                                                  const float* __restrict__ pparam,
                                                  float* __restrict__ le,
                                                  unsigned int* __restrict__ cnt,
                                                  float* __restrict__ out) {
    int idx = blockIdx.x * blockDim.x + threadIdx.x;   // b*CK*D + c*D + d
    int d = idx % D;
    int c = (idx / D) % CK;       // uniform within a block
    int b = idx / (D * CK);

    v2f ph = phazor_of(pparam, d);
    v2f q;  q.x = pinit[d * 2 + 0]; q.y = pinit[d * 2 + 1];
    float hre = hr[(size_t)b * D + d];
    float him = hi[(size_t)b * D + d];

    // ---- phase 1: local scan, keep x in registers ----
    const float* xp = x + ((size_t)b * L + (size_t)c * LC) * D + d;
    float xr[LC];
    float ur = 0.f, ui = 0.f;
#pragma unroll
    for (int i = 0; i < LC; ++i) {
        float xv = xp[(size_t)i * D];
        xr[i] = xv;
        float nr = fmaf(ph.x, ur, fmaf(-ph.y, ui, xv));
        float ni = fmaf(ph.x, ui, ph.y * ur);
        ur = nr; ui = ni;
    }
    if (c != CK - 1) {                      // le[b][CK-1] is never read
        v2f lv; lv.x = ur; lv.y = ui;
        *(v2f*)(le + (size_t)idx * 2) = lv;
    }

    // ---- grid barrier (leader-spin, device scope) ----
    __threadfence();                         // release this thread's le store
    __syncthreads();
    if (threadIdx.x == 0) {
        __hip_atomic_fetch_add(cnt, 1u, __ATOMIC_ACQ_REL, __HIP_MEMORY_SCOPE_AGENT);
        while (__hip_atomic_load(cnt, __ATOMIC_ACQUIRE, __HIP_MEMORY_SCOPE_AGENT)
               < (unsigned int)NBLOCKS) {
            __builtin_amdgcn_s_sleep(2);
        }
    }
    __syncthreads();
    __threadfence();                         // acquire other blocks' le stores

    // ---- phase 2: carry by Horner, then outputs from registers ----
    // P64 = phazor^LC via 6 complex squarings
    float br = ph.x, bi = ph.y;
#pragma unroll
    for (int s = 0; s < 6; ++s) {
        float sr = fmaf(br, br, -bi * bi);
        float si = 2.f * br * bi;
        br = sr; bi = si;
    }

    // carry-in W[c] = sum_{j<c} P64^{c-1-j} * le[b][j][d]  (Horner, ascending j)
    float wr = 0.f, wi = 0.f;
    const float* lp = le + (((size_t)b * CK) * D + d) * 2;
    for (int j = 0; j < c; ++j) {
        v2f lv = *(const v2f*)(lp + (size_t)j * D * 2);
        float tr = fmaf(wr, br, fmaf(-wi, bi, lv.x));
        float ti = fmaf(wr, bi, fmaf(wi, br, lv.y));
        wr = tr; wi = ti;
    }

    // pw = phazor^(c*LC + 1) = P64^c * phazor  (binary exp over 6 bits of c)
    float pwr = ph.x, pwi = ph.y;
    {
        float er = br, ei = bi;
        int n = c;
#pragma unroll
        for (int s = 0; s < 6; ++s) {
            if (n & 1) {
                float tr = fmaf(pwr, er, -pwi * ei);
                float ti = fmaf(pwr, ei, pwi * er);
                pwr = tr; pwi = ti;
            }
            float sr = fmaf(er, er, -ei * ei);
            float si = 2.f * er * ei;
            er = sr; ei = si;
            n >>= 1;
        }
    }

    float* outr = out + ((size_t)b * L + (size_t)c * LC) * D + d;
    float* outr2 = outr + BLD;
    float* outc = out + BLD + (((size_t)b * L + (size_t)c * LC) * D + d) * 2;

    float ur2 = wr, ui2 = wi;               // correct running state
#pragma unroll
    for (int i = 0; i < LC; ++i) {
        float nr = fmaf(ph.x, ur2, fmaf(-ph.y, ui2, xr[i]));
        float ni = fmaf(ph.x, ui2, ph.y * ur2);
        ur2 = nr; ui2 = ni;
        float vr = fmaf(q.x, ur2, fmaf(-q.y, ui2, fmaf(hre, pwr, -him * pwi)));
        float vi = fmaf(q.x, ui2, fmaf(q.y, ur2, fmaf(hre, pwi, him * pwr)));
        outr[(size_t)i * D] = vr;
        if (MODE == 0) {
            outr2[(size_t)i * D] = vr;
        } else {
            v2f vc; vc.x = vr; vc.y = vi;
            *(v2f*)(outc + (size_t)i * D * 2) = vc;
        }
        float tr = fmaf(pwr, ph.x, -pwi * ph.y);
        float ti = fmaf(pwr, ph.y, pwi * ph.x);
        pwr = tr; pwi = ti;
    }
}

// Serial fallback (no scratch): one thread per (b,d), full-L scan.
template <int MODE>
__global__ __launch_bounds__(256) void fallback_k(const float* __restrict__ x,
                                                  const float* __restrict__ hr,
                                                  const float* __restrict__ hi,
                                                  const float* __restrict__ pinit,
                                                  const float* __restrict__ pparam,
                                                  float* __restrict__ out) {
    int idx = blockIdx.x * blockDim.x + threadIdx.x;
    if (idx >= B * D) return;
    int d = idx % D;
    int b = idx / D;
    v2f ph = phazor_of(pparam, d);
    float qr = pinit[d * 2 + 0];
    float qi = pinit[d * 2 + 1];
    float hre = hr[(size_t)b * D + d];
    float him = hi[(size_t)b * D + d];
    float ur = 0.f, ui = 0.f;
    float pwr = ph.x, pwi = ph.y;
    const float* xp = x + (size_t)b * L * D + d;
    float* outr = out + (size_t)b * L * D + d;
    float* outr2 = outr + BLD;
    float* outc = out + BLD + ((size_t)b * L * D + d) * 2;
    for (int t = 0; t < L; ++t) {
        float xv = xp[(size_t)t * D];
        float nr = fmaf(ph.x, ur, fmaf(-ph.y, ui, xv));
        float ni = fmaf(ph.x, ui, ph.y * ur);
        ur = nr; ui = ni;
        float vr = fmaf(qr, ur, fmaf(-qi, ui, fmaf(hre, pwr, -him * pwi)));
        float vi = fmaf(qr, ui, fmaf(qi, ur, fmaf(hre, pwi, him * pwr)));
        outr[(size_t)t * D] = vr;
        if (MODE == 0) {
            outr2[(size_t)t * D] = vr;
        } else {
            v2f vc; vc.x = vr; vc.y = vi;
            *(v2f*)(outc + (size_t)t * D * 2) = vc;
        }
        float tr = fmaf(pwr, ph.x, -pwi * ph.y);
        float ti = fmaf(pwr, ph.y, pwi * ph.x);
        pwr = tr; pwi = ti;
    }
}

extern "C" void kernel_launch(void* const* d_in, const int* in_sizes, int n_in,
                              void* d_out, int out_size, void* d_ws, size_t ws_size,
                              hipStream_t stream) {
    const float* x = (const float*)d_in[0];
    const float* hreal = (const float*)d_in[1];
    const float* himag = (const float*)d_in[2];
    const float* pinit = (const float*)d_in[3];
    const float* pparam = (const float*)d_in[4];
    float* out = (float*)d_out;

    const int mode = (out_size >= (int)(3 * BLD)) ? 1 : 0;

    if (ws_size >= WS_NEED) {
        float* le = (float*)d_ws;
        unsigned int* cnt = (unsigned int*)((char*)d_ws + CNT_BYTE_OFF);
        hipMemsetAsync((void*)cnt, 0, 64, stream);
        if (mode == 0)
            fused_k<0><<<NBLOCKS, 256, 0, stream>>>(x, hreal, himag, pinit, pparam, le, cnt, out);
        else
            fused_k<1><<<NBLOCKS, 256, 0, stream>>>(x, hreal, himag, pinit, pparam, le, cnt, out);
    } else {
        int n = B * D;
        if (mode == 0)
            fallback_k<0><<<(n + 255) / 256, 256, 0, stream>>>(x, hreal, himag, pinit, pparam, out);
        else
            fallback_k<1><<<(n + 255) / 256, 256, 0, stream>>>(x, hreal, himag, pinit, pparam, out);
    }
}

// Round 9
// 62.237 us; speedup vs baseline: 6.1389x; 6.1389x over previous
//
#include <hip/hip_runtime.h>
#include <math.h>

// Problem constants (from reference): x[B][L][D] fp32
#define B 8
#define L 4096
#define D 512
#define LC 32               // chunk length
#define CK (L / LC)         // 128 chunks
#define BLD ((size_t)B * L * D)

#define NTH (B * CK * D)    // 524288 threads -> 8 waves/SIMD

// ws: le [B][CK][D][2] floats = 4 MiB (proven available in round 7).
// carry_k rewrites le in place into exclusive prefix carries W.
#define WS_FLOATS (2 * B * CK * D)

typedef float v2f __attribute__((ext_vector_type(2)));

// phazor = exp(-|z|^2) * z/|z|   (no trig needed)
__device__ __forceinline__ v2f phazor_of(const float* __restrict__ pparam, int d) {
    float a = pparam[d * 2 + 0];
    float bb = pparam[d * 2 + 1];
    float r2 = fmaf(a, a, bb * bb);
    float inv = rsqrtf(r2);
    inv = inv * fmaf(-0.5f * r2 * inv, inv, 1.5f);   // Newton refinement
    float mag = __expf(-r2);
    v2f p; p.x = mag * a * inv; p.y = mag * bb * inv;
    return p;
}

// P32 = phazor^LC via 5 complex squarings
__device__ __forceinline__ v2f p32_of(v2f ph) {
    float br = ph.x, bi = ph.y;
#pragma unroll
    for (int s = 0; s < 5; ++s) {
        float sr = fmaf(br, br, -bi * bi);
        float si = 2.f * br * bi;
        br = sr; bi = si;
    }
    v2f r; r.x = br; r.y = bi;
    return r;
}

// Pass 1: chunk-local scan with zero carry-in; store end state per (b,c,d).
__global__ __launch_bounds__(256) void pass1_k(const float* __restrict__ x,
                                               const float* __restrict__ pparam,
                                               float* __restrict__ le) {
    int idx = blockIdx.x * blockDim.x + threadIdx.x;   // b*CK*D + c*D + d
    int d = idx % D;
    int c = (idx / D) % CK;
    int b = idx / (D * CK);
    v2f ph = phazor_of(pparam, d);
    float ur = 0.f, ui = 0.f;
    const float* xp = x + ((size_t)b * L + (size_t)c * LC) * D + d;
#pragma unroll 8
    for (int i = 0; i < LC; ++i) {
        float xv = xp[(size_t)i * D];
        float nr = fmaf(ph.x, ur, fmaf(-ph.y, ui, xv));
        float ni = fmaf(ph.x, ui, ph.y * ur);
        ur = nr; ui = ni;
    }
    v2f lv; lv.x = ur; lv.y = ui;
    *(v2f*)(le + (size_t)idx * 2) = lv;
}

// Carry: one thread per (b,d). In-place exclusive prefix over c:
//   W[0]=0;  W[c] = P32*W[c-1] + le[c-1]
__global__ __launch_bounds__(256) void carry_k(const float* __restrict__ pparam,
                                               float* __restrict__ le) {
    int idx = blockIdx.x * blockDim.x + threadIdx.x;   // b*D + d
    int d = idx % D;
    int b = idx / D;
    v2f P = p32_of(phazor_of(pparam, d));
    float wr = 0.f, wi = 0.f;
    float* lp = le + (((size_t)b * CK) * D + d) * 2;
#pragma unroll 4
    for (int c = 0; c < CK; ++c) {
        v2f lv = *(const v2f*)(lp + (size_t)c * D * 2);
        v2f wv; wv.x = wr; wv.y = wi;
        *(v2f*)(lp + (size_t)c * D * 2) = wv;
        float tr = fmaf(P.x, wr, fmaf(-P.y, wi, lv.x));
        float ti = fmaf(P.x, wi, fmaf(P.y, wr, lv.y));
        wr = tr; wi = ti;
    }
}

// Pass 2: read carry, re-scan chunk, write outputs.
// MODE 0: out = [real plane][real plane];  MODE 1: [real][interleaved re,im]
template <int MODE>
__global__ __launch_bounds__(256) void pass2_k(const float* __restrict__ x,
                                               const float* __restrict__ hr,
                                               const float* __restrict__ hi,
                                               const float* __restrict__ pinit,
                                               const float* __restrict__ pparam,
                                               const float* __restrict__ le,
                                               float* __restrict__ out) {
    int idx = blockIdx.x * blockDim.x + threadIdx.x;   // b*CK*D + c*D + d
    int d = idx % D;
    int c = (idx / D) % CK;       // uniform within a block
    int b = idx / (D * CK);

    v2f ph = phazor_of(pparam, d);
    v2f q;  q.x = pinit[d * 2 + 0]; q.y = pinit[d * 2 + 1];
    v2f P = p32_of(ph);

    // carry-in (precomputed)
    v2f w = *(const v2f*)(le + (size_t)idx * 2);
    float ur = w.x, ui = w.y;

    // pw = phazor^(c*LC + 1) = P32^c * phazor  (binary exp over 7 bits of c)
    float pwr = ph.x, pwi = ph.y;
    {
        float er = P.x, ei = P.y;
        int n = c;
#pragma unroll
        for (int s = 0; s < 7; ++s) {
            if (n & 1) {
                float tr = fmaf(pwr, er, -pwi * ei);
                float ti = fmaf(pwr, ei, pwi * er);
                pwr = tr; pwi = ti;
            }
            float sr = fmaf(er, er, -ei * ei);
            float si = 2.f * er * ei;
            er = sr; ei = si;
            n >>= 1;
        }
    }

    float hre = hr[(size_t)b * D + d];
    float him = hi[(size_t)b * D + d];

    const float* xp = x + ((size_t)b * L + (size_t)c * LC) * D + d;
    float* outr = out + ((size_t)b * L + (size_t)c * LC) * D + d;
    float* outr2 = outr + BLD;
    float* outc = out + BLD + (((size_t)b * L + (size_t)c * LC) * D + d) * 2;

#pragma unroll 4
    for (int i = 0; i < LC; ++i) {
        float xv = xp[(size_t)i * D];
        float nr = fmaf(ph.x, ur, fmaf(-ph.y, ui, xv));
        float ni = fmaf(ph.x, ui, ph.y * ur);
        ur = nr; ui = ni;
        float vr = fmaf(q.x, ur, fmaf(-q.y, ui, fmaf(hre, pwr, -him * pwi)));
        float vi = fmaf(q.x, ui, fmaf(q.y, ur, fmaf(hre, pwi, him * pwr)));
        outr[(size_t)i * D] = vr;
        if (MODE == 0) {
            outr2[(size_t)i * D] = vr;
        } else {
            v2f vc; vc.x = vr; vc.y = vi;
            *(v2f*)(outc + (size_t)i * D * 2) = vc;
        }
        float tr = fmaf(pwr, ph.x, -pwi * ph.y);
        float ti = fmaf(pwr, ph.y, pwi * ph.x);
        pwr = tr; pwi = ti;
    }
}

// Serial fallback (no scratch): one thread per (b,d), full-L scan.
template <int MODE>
__global__ __launch_bounds__(256) void fallback_k(const float* __restrict__ x,
                                                  const float* __restrict__ hr,
                                                  const float* __restrict__ hi,
                                                  const float* __restrict__ pinit,
                                                  const float* __restrict__ pparam,
                                                  float* __restrict__ out) {
    int idx = blockIdx.x * blockDim.x + threadIdx.x;
    if (idx >= B * D) return;
    int d = idx % D;
    int b = idx / D;
    v2f ph = phazor_of(pparam, d);
    float qr = pinit[d * 2 + 0];
    float qi = pinit[d * 2 + 1];
    float hre = hr[(size_t)b * D + d];
    float him = hi[(size_t)b * D + d];
    float ur = 0.f, ui = 0.f;
    float pwr = ph.x, pwi = ph.y;
    const float* xp = x + (size_t)b * L * D + d;
    float* outr = out + (size_t)b * L * D + d;
    float* outr2 = outr + BLD;
    float* outc = out + BLD + ((size_t)b * L * D + d) * 2;
    for (int t = 0; t < L; ++t) {
        float xv = xp[(size_t)t * D];
        float nr = fmaf(ph.x, ur, fmaf(-ph.y, ui, xv));
        float ni = fmaf(ph.x, ui, ph.y * ur);
        ur = nr; ui = ni;
        float vr = fmaf(qr, ur, fmaf(-qi, ui, fmaf(hre, pwr, -him * pwi)));
        float vi = fmaf(qr, ui, fmaf(qi, ur, fmaf(hre, pwi, him * pwr)));
        outr[(size_t)t * D] = vr;
        if (MODE == 0) {
            outr2[(size_t)t * D] = vr;
        } else {
            v2f vc; vc.x = vr; vc.y = vi;
            *(v2f*)(outc + (size_t)t * D * 2) = vc;
        }
        float tr = fmaf(pwr, ph.x, -pwi * ph.y);
        float ti = fmaf(pwr, ph.y, pwi * ph.x);
        pwr = tr; pwi = ti;
    }
}

extern "C" void kernel_launch(void* const* d_in, const int* in_sizes, int n_in,
                              void* d_out, int out_size, void* d_ws, size_t ws_size,
                              hipStream_t stream) {
    const float* x = (const float*)d_in[0];
    const float* hreal = (const float*)d_in[1];
    const float* himag = (const float*)d_in[2];
    const float* pinit = (const float*)d_in[3];
    const float* pparam = (const float*)d_in[4];
    float* out = (float*)d_out;

    const int mode = (out_size >= (int)(3 * BLD)) ? 1 : 0;

    if (ws_size >= (size_t)WS_FLOATS * sizeof(float)) {
        float* le = (float*)d_ws;
        pass1_k<<<NTH / 256, 256, 0, stream>>>(x, pparam, le);
        carry_k<<<(B * D) / 256, 256, 0, stream>>>(pparam, le);
        if (mode == 0)
            pass2_k<0><<<NTH / 256, 256, 0, stream>>>(x, hreal, himag, pinit, pparam, le, out);
        else
            pass2_k<1><<<NTH / 256, 256, 0, stream>>>(x, hreal, himag, pinit, pparam, le, out);
    } else {
        int n = B * D;
        if (mode == 0)
            fallback_k<0><<<(n + 255) / 256, 256, 0, stream>>>(x, hreal, himag, pinit, pparam, out);
        else
            fallback_k<1><<<(n + 255) / 256, 256, 0, stream>>>(x, hreal, himag, pinit, pparam, out);
    }
}

// Round 10
// 61.750 us; speedup vs baseline: 6.1873x; 1.0079x over previous
//
#include <hip/hip_runtime.h>
#include <math.h>

// Problem constants (from reference): x[B][L][D] fp32
#define B 8
#define L 4096
#define D 512
#define LC 32               // chunk length
#define CK (L / LC)         // 128 chunks
#define BLD ((size_t)B * L * D)

#define NTH (B * CK * D)    // 524288 threads -> 8 waves/SIMD

// ws: le [B][CK][D][2] floats = 4 MiB (proven available).
// carry_k rewrites le in place into exclusive prefix carries W.
#define WS_FLOATS (2 * B * CK * D)

typedef float v2f __attribute__((ext_vector_type(2)));

// phazor = exp(-|z|^2) * z/|z|   (no trig needed)
__device__ __forceinline__ v2f phazor_of(const float* __restrict__ pparam, int d) {
    float a = pparam[d * 2 + 0];
    float bb = pparam[d * 2 + 1];
    float r2 = fmaf(a, a, bb * bb);
    float inv = rsqrtf(r2);
    inv = inv * fmaf(-0.5f * r2 * inv, inv, 1.5f);   // Newton refinement
    float mag = __expf(-r2);
    v2f p; p.x = mag * a * inv; p.y = mag * bb * inv;
    return p;
}

// P32 = phazor^LC via 5 complex squarings
__device__ __forceinline__ v2f p32_of(v2f ph) {
    float br = ph.x, bi = ph.y;
#pragma unroll
    for (int s = 0; s < 5; ++s) {
        float sr = fmaf(br, br, -bi * bi);
        float si = 2.f * br * bi;
        br = sr; bi = si;
    }
    v2f r; r.x = br; r.y = bi;
    return r;
}

// Pass 1: chunk-local scan with zero carry-in; store end state per (b,c,d).
__global__ __launch_bounds__(256) void pass1_k(const float* __restrict__ x,
                                               const float* __restrict__ pparam,
                                               float* __restrict__ le) {
    int idx = blockIdx.x * blockDim.x + threadIdx.x;   // b*CK*D + c*D + d
    int d = idx % D;
    int c = (idx / D) % CK;
    int b = idx / (D * CK);
    v2f ph = phazor_of(pparam, d);
    float ur = 0.f, ui = 0.f;
    const float* xp = x + ((size_t)b * L + (size_t)c * LC) * D + d;
#pragma unroll 8
    for (int i = 0; i < LC; ++i) {
        float xv = xp[(size_t)i * D];
        float nr = fmaf(ph.x, ur, fmaf(-ph.y, ui, xv));
        float ni = fmaf(ph.x, ui, ph.y * ur);
        ur = nr; ui = ni;
    }
    v2f lv; lv.x = ur; lv.y = ui;
    *(v2f*)(le + (size_t)idx * 2) = lv;
}

// Carry: one thread per (b,d), launched as 64-thread blocks (64 blocks ->
// spread over 64 CUs; 16 fat blocks was per-CU-BW-bound, ~22 us in R9).
// In-place exclusive prefix over c:  W[0]=0;  W[c] = P32*W[c-1] + le[c-1]
__global__ __launch_bounds__(64) void carry_k(const float* __restrict__ pparam,
                                              float* __restrict__ le) {
    int idx = blockIdx.x * blockDim.x + threadIdx.x;   // b*D + d
    int d = idx % D;
    int b = idx / D;
    v2f P = p32_of(phazor_of(pparam, d));
    float wr = 0.f, wi = 0.f;
    float* lp = le + (((size_t)b * CK) * D + d) * 2;
#pragma unroll 4
    for (int c = 0; c < CK; ++c) {
        v2f lv = *(const v2f*)(lp + (size_t)c * D * 2);
        v2f wv; wv.x = wr; wv.y = wi;
        *(v2f*)(lp + (size_t)c * D * 2) = wv;
        float tr = fmaf(P.x, wr, fmaf(-P.y, wi, lv.x));
        float ti = fmaf(P.x, wi, fmaf(P.y, wr, lv.y));
        wr = tr; wi = ti;
    }
}

// Pass 2: read carry, re-scan chunk, write outputs.
// MODE 0: out = [real plane][real plane];  MODE 1: [real][interleaved re,im]
template <int MODE>
__global__ __launch_bounds__(256) void pass2_k(const float* __restrict__ x,
                                               const float* __restrict__ hr,
                                               const float* __restrict__ hi,
                                               const float* __restrict__ pinit,
                                               const float* __restrict__ pparam,
                                               const float* __restrict__ le,
                                               float* __restrict__ out) {
    int idx = blockIdx.x * blockDim.x + threadIdx.x;   // b*CK*D + c*D + d
    int d = idx % D;
    int c = (idx / D) % CK;       // uniform within a block
    int b = idx / (D * CK);

    v2f ph = phazor_of(pparam, d);
    v2f q;  q.x = pinit[d * 2 + 0]; q.y = pinit[d * 2 + 1];
    v2f P = p32_of(ph);

    // carry-in (precomputed)
    v2f w = *(const v2f*)(le + (size_t)idx * 2);
    float ur = w.x, ui = w.y;

    // pw = phazor^(c*LC + 1) = P32^c * phazor  (binary exp over 7 bits of c)
    float pwr = ph.x, pwi = ph.y;
    {
        float er = P.x, ei = P.y;
        int n = c;
#pragma unroll
        for (int s = 0; s < 7; ++s) {
            if (n & 1) {
                float tr = fmaf(pwr, er, -pwi * ei);
                float ti = fmaf(pwr, ei, pwi * er);
                pwr = tr; pwi = ti;
            }
            float sr = fmaf(er, er, -ei * ei);
            float si = 2.f * er * ei;
            er = sr; ei = si;
            n >>= 1;
        }
    }

    float hre = hr[(size_t)b * D + d];
    float him = hi[(size_t)b * D + d];

    const float* xp = x + ((size_t)b * L + (size_t)c * LC) * D + d;
    float* outr = out + ((size_t)b * L + (size_t)c * LC) * D + d;
    float* outr2 = outr + BLD;
    float* outc = out + BLD + (((size_t)b * L + (size_t)c * LC) * D + d) * 2;

#pragma unroll 4
    for (int i = 0; i < LC; ++i) {
        float xv = xp[(size_t)i * D];
        float nr = fmaf(ph.x, ur, fmaf(-ph.y, ui, xv));
        float ni = fmaf(ph.x, ui, ph.y * ur);
        ur = nr; ui = ni;
        float vr = fmaf(q.x, ur, fmaf(-q.y, ui, fmaf(hre, pwr, -him * pwi)));
        float vi = fmaf(q.x, ui, fmaf(q.y, ur, fmaf(hre, pwi, him * pwr)));
        outr[(size_t)i * D] = vr;
        if (MODE == 0) {
            outr2[(size_t)i * D] = vr;
        } else {
            v2f vc; vc.x = vr; vc.y = vi;
            *(v2f*)(outc + (size_t)i * D * 2) = vc;
        }
        float tr = fmaf(pwr, ph.x, -pwi * ph.y);
        float ti = fmaf(pwr, ph.y, pwi * ph.x);
        pwr = tr; pwi = ti;
    }
}

// Serial fallback (no scratch): one thread per (b,d), full-L scan.
template <int MODE>
__global__ __launch_bounds__(256) void fallback_k(const float* __restrict__ x,
                                                  const float* __restrict__ hr,
                                                  const float* __restrict__ hi,
                                                  const float* __restrict__ pinit,
                                                  const float* __restrict__ pparam,
                                                  float* __restrict__ out) {
    int idx = blockIdx.x * blockDim.x + threadIdx.x;
    if (idx >= B * D) return;
    int d = idx % D;
    int b = idx / D;
    v2f ph = phazor_of(pparam, d);
    float qr = pinit[d * 2 + 0];
    float qi = pinit[d * 2 + 1];
    float hre = hr[(size_t)b * D + d];
    float him = hi[(size_t)b * D + d];
    float ur = 0.f, ui = 0.f;
    float pwr = ph.x, pwi = ph.y;
    const float* xp = x + (size_t)b * L * D + d;
    float* outr = out + (size_t)b * L * D + d;
    float* outr2 = outr + BLD;
    float* outc = out + BLD + ((size_t)b * L * D + d) * 2;
    for (int t = 0; t < L; ++t) {
        float xv = xp[(size_t)t * D];
        float nr = fmaf(ph.x, ur, fmaf(-ph.y, ui, xv));
        float ni = fmaf(ph.x, ui, ph.y * ur);
        ur = nr; ui = ni;
        float vr = fmaf(qr, ur, fmaf(-qi, ui, fmaf(hre, pwr, -him * pwi)));
        float vi = fmaf(qr, ui, fmaf(qi, ur, fmaf(hre, pwi, him * pwr)));
        outr[(size_t)t * D] = vr;
        if (MODE == 0) {
            outr2[(size_t)t * D] = vr;
        } else {
            v2f vc; vc.x = vr; vc.y = vi;
            *(v2f*)(outc + (size_t)t * D * 2) = vc;
        }
        float tr = fmaf(pwr, ph.x, -pwi * ph.y);
        float ti = fmaf(pwr, ph.y, pwi * ph.x);
        pwr = tr; pwi = ti;
    }
}

extern "C" void kernel_launch(void* const* d_in, const int* in_sizes, int n_in,
                              void* d_out, int out_size, void* d_ws, size_t ws_size,
                              hipStream_t stream) {
    const float* x = (const float*)d_in[0];
    const float* hreal = (const float*)d_in[1];
    const float* himag = (const float*)d_in[2];
    const float* pinit = (const float*)d_in[3];
    const float* pparam = (const float*)d_in[4];
    float* out = (float*)d_out;

    const int mode = (out_size >= (int)(3 * BLD)) ? 1 : 0;

    if (ws_size >= (size_t)WS_FLOATS * sizeof(float)) {
        float* le = (float*)d_ws;
        pass1_k<<<NTH / 256, 256, 0, stream>>>(x, pparam, le);
        carry_k<<<(B * D) / 64, 64, 0, stream>>>(pparam, le);   // 64 blocks -> 64 CUs
        if (mode == 0)
            pass2_k<0><<<NTH / 256, 256, 0, stream>>>(x, hreal, himag, pinit, pparam, le, out);
        else
            pass2_k<1><<<NTH / 256, 256, 0, stream>>>(x, hreal, himag, pinit, pparam, le, out);
    } else {
        int n = B * D;
        if (mode == 0)
            fallback_k<0><<<(n + 255) / 256, 256, 0, stream>>>(x, hreal, himag, pinit, pparam, out);
        else
            fallback_k<1><<<(n + 255) / 256, 256, 0, stream>>>(x, hreal, himag, pinit, pparam, out);
    }
}